// Round 1
// baseline (566.782 us; speedup 1.0000x reference)
//
#include <hip/hip_runtime.h>
#include <hip/hip_bf16.h>

// Per-token head-attention, fused: qkv projection (MFMA) + 8x8 softmax + PV.
// B=16, N=4096, C=1024, H=8, DH=128. Tokens = 65536.
// TB=8 tokens per workgroup (4 waves); wave owns 32-col N-slice in phase 1,
// one token-pair in phase 2.

typedef short s16x8 __attribute__((ext_vector_type(8)));
typedef float f32x4 __attribute__((ext_vector_type(4)));

#define NHEAD 8
#define DHEAD 128
#define TB 8
#define MROWS 64           // TB*NHEAD
#define QK_STRIDE 136      // shorts; 272B rows -> 16B aligned, 2-way banks (free)
#define VT_STRIDE 80       // shorts; 160B rows -> 16B aligned

__device__ __forceinline__ short f2bf(float f) {
    union { __hip_bfloat16 h; short s; } u;
    u.h = __float2bfloat16(f);
    return u.s;
}

__global__ __launch_bounds__(256, 2)
void fused_head_attn(const float* __restrict__ x,
                     const float* __restrict__ Wq,
                     const float* __restrict__ Wk,
                     const float* __restrict__ Wv,
                     float* __restrict__ out)
{
    __shared__ short q_s[MROWS * QK_STRIDE];
    __shared__ short k_s[MROWS * QK_STRIDE];
    __shared__ short v_t[DHEAD * VT_STRIDE];   // v transposed: [d][row]

    const int tid  = threadIdx.x;
    const int wave = tid >> 6;
    const int lane = tid & 63;
    const int lr   = lane & 15;   // M-row (A) or N-col (B) selector
    const int lq   = lane >> 4;   // quarter -> K offset

    const long tok_base = (long)blockIdx.x * TB;
    const float* x_tile = x + tok_base * 1024;

    // zero v_t overhang cols [64,80) so PV's padded-K reads can't see NaN
    {
        int r = tid >> 1, half = tid & 1;
        *reinterpret_cast<int4*>(&v_t[r * VT_STRIDE + 64 + half * 8]) =
            make_int4(0, 0, 0, 0);
    }

    // ---------------- Phase 1: q,k,v = xh @ W (M=64, N=128 split 4 ways, K=128)
    // A-frags: x rows as bf16, 16 frags [m][kk]
    s16x8 afrag[4][4];
    #pragma unroll
    for (int m = 0; m < 4; ++m) {
        #pragma unroll
        for (int kk = 0; kk < 4; ++kk) {
            const float* p = x_tile + (m * 16 + lr) * 128 + kk * 32 + lq * 8;
            float4 u0 = *reinterpret_cast<const float4*>(p);
            float4 u1 = *reinterpret_cast<const float4*>(p + 4);
            s16x8 a;
            a[0] = f2bf(u0.x); a[1] = f2bf(u0.y); a[2] = f2bf(u0.z); a[3] = f2bf(u0.w);
            a[4] = f2bf(u1.x); a[5] = f2bf(u1.y); a[6] = f2bf(u1.z); a[7] = f2bf(u1.w);
            afrag[m][kk] = a;
        }
    }

    const int colbase = wave * 32;
    const float* Ws[3] = {Wq, Wk, Wv};
    #pragma unroll
    for (int mat = 0; mat < 3; ++mat) {
        const float* W = Ws[mat];
        // B-frags: W^T gathered (L2-resident), 8 frags [n][kk]
        s16x8 bfrag[2][4];
        #pragma unroll
        for (int n = 0; n < 2; ++n) {
            int col = colbase + n * 16 + lr;
            #pragma unroll
            for (int kk = 0; kk < 4; ++kk) {
                int k0 = kk * 32 + lq * 8;
                s16x8 b;
                #pragma unroll
                for (int j = 0; j < 8; ++j)
                    b[j] = f2bf(W[(k0 + j) * 128 + col]);
                bfrag[n][kk] = b;
            }
        }
        #pragma unroll
        for (int m = 0; m < 4; ++m) {
            #pragma unroll
            for (int n = 0; n < 2; ++n) {
                f32x4 acc = {0.f, 0.f, 0.f, 0.f};
                #pragma unroll
                for (int kk = 0; kk < 4; ++kk)
                    acc = __builtin_amdgcn_mfma_f32_16x16x32_bf16(
                        afrag[m][kk], bfrag[n][kk], acc, 0, 0, 0);
                const int col   = colbase + n * 16 + lr;
                const int rbase = m * 16 + lq * 4;
                if (mat == 0) {
                    #pragma unroll
                    for (int r = 0; r < 4; ++r)
                        q_s[(rbase + r) * QK_STRIDE + col] = f2bf(acc[r]);
                } else if (mat == 1) {
                    #pragma unroll
                    for (int r = 0; r < 4; ++r)
                        k_s[(rbase + r) * QK_STRIDE + col] = f2bf(acc[r]);
                } else {
                    short4 pk;
                    pk.x = f2bf(acc[0]); pk.y = f2bf(acc[1]);
                    pk.z = f2bf(acc[2]); pk.w = f2bf(acc[3]);
                    *reinterpret_cast<short4*>(&v_t[col * VT_STRIDE + rbase]) = pk;
                }
            }
        }
    }

    __syncthreads();

    // ---------------- Phase 2: wave handles token pair -> rows [rb, rb+16)
    const int rb = wave * 16;

    s16x8 qf[4], kf[4];
    #pragma unroll
    for (int kk = 0; kk < 4; ++kk) {
        qf[kk] = *reinterpret_cast<const s16x8*>(
            &q_s[(rb + lr) * QK_STRIDE + kk * 32 + lq * 8]);
        kf[kk] = *reinterpret_cast<const s16x8*>(
            &k_s[(rb + lr) * QK_STRIDE + kk * 32 + lq * 8]);
    }
    f32x4 aff = {0.f, 0.f, 0.f, 0.f};
    #pragma unroll
    for (int kk = 0; kk < 4; ++kk)
        aff = __builtin_amdgcn_mfma_f32_16x16x32_bf16(qf[kk], kf[kk], aff, 0, 0, 0);

    // aff[r] is element (row = lq*4+r, col = lr) of the 16x16 pair tile.
    // valid iff both indices in the same token's 8-half.
    const float scale = 0.0078125f;   // H / K_DIM = 8/1024
    const bool valid  = (lr < 8) == (lq < 2);
    float p[4];
    #pragma unroll
    for (int r = 0; r < 4; ++r) {
        float s0 = aff[r] * scale;
        float mx = s0;
        mx = fmaxf(mx, __shfl_xor(mx, 1));
        mx = fmaxf(mx, __shfl_xor(mx, 2));
        mx = fmaxf(mx, __shfl_xor(mx, 4));
        float e = __expf(s0 - mx);
        float sum = e;
        sum += __shfl_xor(sum, 1);
        sum += __shfl_xor(sum, 2);
        sum += __shfl_xor(sum, 4);
        p[r] = valid ? (e / sum) : 0.f;
    }

    // Stage P (bf16, zero-padded to K=32) into the wave's dead q_s rows.
    if (lane < 32) {   // zero cols [16,32) of all 16 rows
        *reinterpret_cast<int4*>(&q_s[(rb + lr) * QK_STRIDE + 16 + lq * 8]) =
            make_int4(0, 0, 0, 0);
    }
    {
        const int rbase = rb + lq * 4;
        #pragma unroll
        for (int r = 0; r < 4; ++r)
            q_s[(rbase + r) * QK_STRIDE + lr] = f2bf(p[r]);
    }
    asm volatile("s_waitcnt lgkmcnt(0)" ::: "memory");
    __builtin_amdgcn_sched_barrier(0);

    s16x8 pa = *reinterpret_cast<const s16x8*>(&q_s[(rb + lr) * QK_STRIDE + lq * 8]);

    // PV: ctx(16x128) = P(16x16, padded 32) @ v ; B from v_t (contiguous K).
    float* out_tile = out + tok_base * 1024 + (long)wave * 2048;
    #pragma unroll
    for (int nf = 0; nf < 8; ++nf) {
        s16x8 bv = *reinterpret_cast<const s16x8*>(
            &v_t[(nf * 16 + lr) * VT_STRIDE + rb + lq * 8]);
        f32x4 c = {0.f, 0.f, 0.f, 0.f};
        c = __builtin_amdgcn_mfma_f32_16x16x32_bf16(pa, bv, c, 0, 0, 0);
        #pragma unroll
        for (int r = 0; r < 4; ++r)
            out_tile[(lq * 4 + r) * 128 + nf * 16 + lr] = c[r];
    }
}

extern "C" void kernel_launch(void* const* d_in, const int* in_sizes, int n_in,
                              void* d_out, int out_size, void* d_ws, size_t ws_size,
                              hipStream_t stream) {
    const float* x  = (const float*)d_in[0];
    const float* Wq = (const float*)d_in[1];
    const float* Wk = (const float*)d_in[2];
    const float* Wv = (const float*)d_in[3];
    float* outp = (float*)d_out;

    const int tokens = 16 * 4096;          // B*N
    dim3 grid(tokens / TB), block(256);
    fused_head_attn<<<grid, block, 0, stream>>>(x, Wq, Wk, Wv, outp);
}

// Round 2
// 540.268 us; speedup vs baseline: 1.0491x; 1.0491x over previous
//
#include <hip/hip_runtime.h>
#include <hip/hip_bf16.h>

// Per-token head-attention, fused: qkv projection (MFMA) + 8x8 softmax + PV.
// B=16, N=4096, C=1024, H=8, DH=128. Tokens = 65536.
// TB=8 tokens per workgroup (4 waves); wave owns 32-col N-slice in phase 1,
// one token-pair in phase 2.
// R2: weights pre-converted to bf16 W^T (fragment-order) in d_ws by a tiny
//     pre-kernel; LDS 55296->53248 B (3 WG/CU); clamp dead PV lanes instead
//     of pad rows.

typedef short s16x8 __attribute__((ext_vector_type(8)));
typedef float f32x4 __attribute__((ext_vector_type(4)));

#define NHEAD 8
#define DHEAD 128
#define TB 8
#define MROWS 64           // TB*NHEAD
#define QK_STRIDE 136      // shorts; 272B rows -> 16B aligned, banks 4*lr mod 32
#define VT_STRIDE 72       // shorts; 144B rows -> 16B aligned, banks 4*lr mod 32

__device__ __forceinline__ short f2bf(float f) {
    union { __hip_bfloat16 h; short s; } u;
    u.h = __float2bfloat16(f);
    return u.s;
}

// ---- pre-kernel: Wt_bf16[mat][col][k] = bf16(W[k][col]); 3*128*128 elems ----
__global__ void conv_weights(const float* __restrict__ Wq,
                             const float* __restrict__ Wk,
                             const float* __restrict__ Wv,
                             short* __restrict__ wt)
{
    int i = blockIdx.x * 256 + threadIdx.x;     // 49152 total
    int mat = i >> 14;
    int r   = i & 16383;
    int c   = r >> 7;      // col (output dim)
    int k   = r & 127;     // input dim
    const float* W = (mat == 0) ? Wq : ((mat == 1) ? Wk : Wv);
    wt[i] = f2bf(W[k * 128 + c]);
}

__global__ __launch_bounds__(256, 3)
void fused_head_attn(const float* __restrict__ x,
                     const short* __restrict__ wt,
                     float* __restrict__ out)
{
    __shared__ short q_s[MROWS * QK_STRIDE];
    __shared__ short k_s[MROWS * QK_STRIDE];
    __shared__ short v_t[DHEAD * VT_STRIDE];   // v transposed: [d][row]

    const int tid  = threadIdx.x;
    const int wave = tid >> 6;
    const int lane = tid & 63;
    const int lr   = lane & 15;   // M-row (A) or N-col (B) selector
    const int lq   = lane >> 4;   // quarter -> K offset

    const long tok_base = (long)blockIdx.x * TB;
    const float* x_tile = x + tok_base * 1024;

    // ---------------- Phase 1: q,k,v = xh @ W (M=64, N=128 split 4 ways, K=128)
    // A-frags: x rows as bf16, 16 frags [m][kk]
    s16x8 afrag[4][4];
    #pragma unroll
    for (int m = 0; m < 4; ++m) {
        #pragma unroll
        for (int kk = 0; kk < 4; ++kk) {
            const float* p = x_tile + (m * 16 + lr) * 128 + kk * 32 + lq * 8;
            float4 u0 = *reinterpret_cast<const float4*>(p);
            float4 u1 = *reinterpret_cast<const float4*>(p + 4);
            s16x8 a;
            a[0] = f2bf(u0.x); a[1] = f2bf(u0.y); a[2] = f2bf(u0.z); a[3] = f2bf(u0.w);
            a[4] = f2bf(u1.x); a[5] = f2bf(u1.y); a[6] = f2bf(u1.z); a[7] = f2bf(u1.w);
            afrag[m][kk] = a;
        }
    }

    const int colbase = wave * 32;
    #pragma unroll
    for (int mat = 0; mat < 3; ++mat) {
        const short* Wt = wt + mat * 16384;
        // B-frags: one 16B vector load each (L2-resident, fragment-ordered)
        s16x8 bfrag[2][4];
        #pragma unroll
        for (int n = 0; n < 2; ++n) {
            int col = colbase + n * 16 + lr;
            #pragma unroll
            for (int kk = 0; kk < 4; ++kk)
                bfrag[n][kk] = *reinterpret_cast<const s16x8*>(
                    Wt + col * 128 + kk * 32 + lq * 8);
        }
        #pragma unroll
        for (int m = 0; m < 4; ++m) {
            #pragma unroll
            for (int n = 0; n < 2; ++n) {
                f32x4 acc = {0.f, 0.f, 0.f, 0.f};
                #pragma unroll
                for (int kk = 0; kk < 4; ++kk)
                    acc = __builtin_amdgcn_mfma_f32_16x16x32_bf16(
                        afrag[m][kk], bfrag[n][kk], acc, 0, 0, 0);
                const int col   = colbase + n * 16 + lr;
                const int rbase = m * 16 + lq * 4;
                if (mat == 0) {
                    #pragma unroll
                    for (int r = 0; r < 4; ++r)
                        q_s[(rbase + r) * QK_STRIDE + col] = f2bf(acc[r]);
                } else if (mat == 1) {
                    #pragma unroll
                    for (int r = 0; r < 4; ++r)
                        k_s[(rbase + r) * QK_STRIDE + col] = f2bf(acc[r]);
                } else {
                    short4 pk;
                    pk.x = f2bf(acc[0]); pk.y = f2bf(acc[1]);
                    pk.z = f2bf(acc[2]); pk.w = f2bf(acc[3]);
                    *reinterpret_cast<short4*>(&v_t[col * VT_STRIDE + rbase]) = pk;
                }
            }
        }
    }

    __syncthreads();

    // ---------------- Phase 2: wave handles token pair -> rows [rb, rb+16)
    const int rb = wave * 16;

    s16x8 qf[4], kf[4];
    #pragma unroll
    for (int kk = 0; kk < 4; ++kk) {
        qf[kk] = *reinterpret_cast<const s16x8*>(
            &q_s[(rb + lr) * QK_STRIDE + kk * 32 + lq * 8]);
        kf[kk] = *reinterpret_cast<const s16x8*>(
            &k_s[(rb + lr) * QK_STRIDE + kk * 32 + lq * 8]);
    }
    f32x4 aff = {0.f, 0.f, 0.f, 0.f};
    #pragma unroll
    for (int kk = 0; kk < 4; ++kk)
        aff = __builtin_amdgcn_mfma_f32_16x16x32_bf16(qf[kk], kf[kk], aff, 0, 0, 0);

    // aff[r] is element (row = lq*4+r, col = lr) of the 16x16 pair tile.
    // valid iff both indices in the same token's 8-half.
    const float scale = 0.0078125f;   // H / K_DIM = 8/1024
    const bool valid  = (lr < 8) == (lq < 2);
    float p[4];
    #pragma unroll
    for (int r = 0; r < 4; ++r) {
        float s0 = aff[r] * scale;
        float mx = s0;
        mx = fmaxf(mx, __shfl_xor(mx, 1));
        mx = fmaxf(mx, __shfl_xor(mx, 2));
        mx = fmaxf(mx, __shfl_xor(mx, 4));
        float e = __expf(s0 - mx);
        float sum = e;
        sum += __shfl_xor(sum, 1);
        sum += __shfl_xor(sum, 2);
        sum += __shfl_xor(sum, 4);
        p[r] = valid ? (e / sum) : 0.f;
    }

    // Stage P (bf16, zero-padded to K=32) into the wave's dead q_s rows.
    if (lane < 32) {   // zero cols [16,32) of all 16 rows
        *reinterpret_cast<int4*>(&q_s[(rb + lr) * QK_STRIDE + 16 + lq * 8]) =
            make_int4(0, 0, 0, 0);
    }
    {
        const int rbase = rb + lq * 4;
        #pragma unroll
        for (int r = 0; r < 4; ++r)
            q_s[(rbase + r) * QK_STRIDE + lr] = f2bf(p[r]);
    }
    asm volatile("s_waitcnt lgkmcnt(0)" ::: "memory");
    __builtin_amdgcn_sched_barrier(0);

    s16x8 pa = *reinterpret_cast<const s16x8*>(&q_s[(rb + lr) * QK_STRIDE + lq * 8]);

    // PV: ctx(16x128) = P(16x16, padded 32) @ v ; B from v_t (contiguous K).
    // Lanes lq>=2 carry zero P values; clamp their v-row window into valid
    // rows (finite garbage * 0) instead of keeping pad rows in LDS.
    const int vk = rb + (lq & 1) * 8;
    float* out_tile = out + tok_base * 1024 + (long)wave * 2048;
    #pragma unroll
    for (int nf = 0; nf < 8; ++nf) {
        s16x8 bv = *reinterpret_cast<const s16x8*>(
            &v_t[(nf * 16 + lr) * VT_STRIDE + vk]);
        f32x4 c = {0.f, 0.f, 0.f, 0.f};
        c = __builtin_amdgcn_mfma_f32_16x16x32_bf16(pa, bv, c, 0, 0, 0);
        #pragma unroll
        for (int r = 0; r < 4; ++r)
            out_tile[(lq * 4 + r) * 128 + nf * 16 + lr] = c[r];
    }
}

extern "C" void kernel_launch(void* const* d_in, const int* in_sizes, int n_in,
                              void* d_out, int out_size, void* d_ws, size_t ws_size,
                              hipStream_t stream) {
    const float* x  = (const float*)d_in[0];
    const float* Wq = (const float*)d_in[1];
    const float* Wk = (const float*)d_in[2];
    const float* Wv = (const float*)d_in[3];
    float* outp = (float*)d_out;
    short* wt   = (short*)d_ws;            // 3*128*128 bf16 = 96 KB

    conv_weights<<<dim3(192), dim3(256), 0, stream>>>(Wq, Wk, Wv, wt);

    const int tokens = 16 * 4096;          // B*N
    dim3 grid(tokens / TB), block(256);
    fused_head_attn<<<grid, block, 0, stream>>>(x, wt, outp);
}